// Round 7
// baseline (78.152 us; speedup 1.0000x reference)
//
#include <hip/hip_runtime.h>

#define Hd 64
#define Wd 256
#define HWd 16384
#define NPTS 16384

#define F(x) __int_as_float(x)

// ---- Device port of glibc/msun flt-32 atanf (5-coefficient version) ----
__device__ __forceinline__ float fd_atanf(float x) {
    int hx = __float_as_int(x);
    int ix = hx & 0x7fffffff;
    if (ix >= 0x4c800000) {                    // |x| >= 2^26
        if (ix > 0x7f800000) return x;         // NaN
        float r = __fadd_rn(F(0x3FC90FDA), F(0x33A22168));
        return (hx > 0) ? r : -r;
    }
    int id;
    if (ix < 0x3ee00000) {                     // |x| < 0.4375
        if (ix < 0x39800000) return x;         // |x| < 2^-12
        id = -1;
    } else {
        x = F(ix);                             // fabsf
        if (ix < 0x3f980000) {                 // |x| < 1.1875
            if (ix < 0x3f300000) {             // 7/16 <= |x| < 11/16
                id = 0;
                x = __fdiv_rn(__fsub_rn(__fadd_rn(x, x), 1.0f), __fadd_rn(2.0f, x));
            } else {                           // 11/16 <= |x| < 19/16
                id = 1;
                x = __fdiv_rn(__fsub_rn(x, 1.0f), __fadd_rn(x, 1.0f));
            }
        } else {
            if (ix < 0x401c0000) {             // |x| < 2.4375
                id = 2;
                x = __fdiv_rn(__fsub_rn(x, 1.5f), __fadd_rn(1.0f, __fmul_rn(1.5f, x)));
            } else {                           // 2.4375 <= |x| < 2^26
                id = 3;
                x = __fdiv_rn(-1.0f, x);
            }
        }
    }
    // msun 5-coefficient split polynomial
    float z = __fmul_rn(x, x);
    float w = __fmul_rn(z, z);
    float s1 = __fmul_rn(z, __fadd_rn(F(0x3EAAAAA3),
                    __fmul_rn(w, __fadd_rn(F(0x3E11F50D),
                    __fmul_rn(w, F(0x3D7CAC25))))));
    float s2 = __fmul_rn(w, __fadd_rn(F(0xBE4CCA17),
                    __fmul_rn(w, F(0xBDDA1247))));
    float ss = __fadd_rn(s1, s2);
    if (id < 0) return __fsub_rn(x, __fmul_rn(x, ss));
    const float athi[4] = {F(0x3EED6338), F(0x3F490FDA), F(0x3F7B985E), F(0x3FC90FDA)};
    const float atlo[4] = {F(0x31AC3769), F(0x33222168), F(0x33140FB4), F(0x33A22168)};
    float zr = __fsub_rn(athi[id], __fsub_rn(__fsub_rn(__fmul_rn(x, ss), atlo[id]), x));
    return (hx < 0) ? -zr : zr;
}

// ---- Device port of glibc/msun flt-32 atan2f wrapper ----
__device__ __forceinline__ float fd_atan2f(float y, float x) {
    const float pi     = F(0x40490FDB);
    const float pi_lo  = F(0xB3BBBD2E);
    const float pi_o_2 = F(0x3FC90FDB);
    int hx = __float_as_int(x), ix = hx & 0x7fffffff;
    int hy = __float_as_int(y), iy = hy & 0x7fffffff;
    if (ix > 0x7f800000 || iy > 0x7f800000) return x + y;  // NaN
    if (hx == 0x3f800000) return fd_atanf(y);              // x == 1.0
    int m = ((hy >> 31) & 1) | ((hx >> 30) & 2);
    if (iy == 0) {
        switch (m) { case 0: case 1: return y; case 2: return pi; default: return -pi; }
    }
    if (ix == 0) return (hy < 0) ? -pi_o_2 : pi_o_2;
    if (ix == 0x7f800000) {
        if (iy == 0x7f800000) {
            switch (m) {
                case 0: return F(0x3F490FDB);
                case 1: return -F(0x3F490FDB);
                case 2: return __fmul_rn(3.0f, F(0x3F490FDB));
                default: return -__fmul_rn(3.0f, F(0x3F490FDB));
            }
        } else {
            switch (m) { case 0: return 0.0f; case 1: return -0.0f; case 2: return pi; default: return -pi; }
        }
    }
    if (iy == 0x7f800000) return (hy < 0) ? -pi_o_2 : pi_o_2;
    int k = (iy - ix) >> 23;      // approx exponent difference
    float z;
    if (k > 26) { z = __fadd_rn(pi_o_2, __fmul_rn(0.5f, pi_lo)); m &= 1; }
    else if (hx < 0 && k < -26) z = 0.0f;
    else z = fd_atanf(__fdiv_rn(F(iy), F(ix)));  // atanf(fabsf(y/x))
    switch (m) {
        case 0: return z;
        case 1: return -z;
        case 2: return __fsub_rn(pi, __fsub_rn(z, pi_lo));
        default: return __fsub_rn(__fsub_rn(z, pi_lo), pi);
    }
}

// f32 replica of the ref's expansion-formula d2 argmin on the 3x3 window.
// NEW (R7): the einsum dot is computed GEMM-style with FMA accumulation:
//   k=0: acc = rn(au*gu)   (fma with 0)
//   k=1: acc = fma(av, gv, acc)   <- single-rounded second product
// 2*dot is exact (power of two); outer ops stay plain _rn (eager, unfused).
__device__ __forceinline__ int argmin9(float au, float av, int bh, int bw,
                                       const float* s_eu, const float* s_eu2,
                                       const float* s_ev, const float* s_ev2) {
    float asq = __fadd_rn(__fmul_rn(au, au), __fmul_rn(av, av));
    float bestd = 3.4e38f; int besti = 0x7fffffff;
    #pragma unroll
    for (int dh = -1; dh <= 1; ++dh) {
        int hh = bh + dh; hh = hh < 0 ? 0 : (hh > Hd - 1 ? Hd - 1 : hh);
        #pragma unroll
        for (int dw = -1; dw <= 1; ++dw) {
            int ww = bw + dw; ww = ww < 0 ? 0 : (ww > Wd - 1 ? Wd - 1 : ww);
            float gsq = __fadd_rn(s_eu2[hh], s_ev2[ww]);
            float dot = __builtin_fmaf(av, s_ev[ww], __fmul_rn(au, s_eu[hh]));
            float d2  = __fsub_rn(__fadd_rn(asq, gsq), __fmul_rn(2.0f, dot));
            int idx = hh * Wd + ww;
            if (d2 < bestd || (d2 == bestd && idx < besti)) { bestd = d2; besti = idx; }
        }
    }
    return besti;
}

__global__ __launch_bounds__(256) void proj_scatter(
        const float* __restrict__ xyz,
        const float* __restrict__ angle,
        float* __restrict__ num,
        float* __restrict__ den) {
    __shared__ float s_eu[Hd], s_eu2[Hd];
    __shared__ float s_ev[Wd], s_ev2[Wd];

    int t = threadIdx.x;
    if (t < Hd) {
        float e = angle[t * Wd];          // channel 0 (elev), row t, col 0
        s_eu[t]  = e;
        s_eu2[t] = __fmul_rn(e, e);
    }
    {
        float a = angle[HWd + t];         // channel 1 (azim), row 0, col t
        s_ev[t]  = a;
        s_ev2[t] = __fmul_rn(a, a);
    }
    __syncthreads();

    int n = blockIdx.x * blockDim.x + t;
    if (n >= NPTS) return;

    float x = xyz[3 * n + 0];
    float y = xyz[3 * n + 1];
    float z = xyz[3 * n + 2];

    // Replicate f32 norm rounding order: ((x^2+y^2)+z^2)
    float xx = __fmul_rn(x, x);
    float yy = __fmul_rn(y, y);
    float zz = __fmul_rn(z, z);
    float r2 = __fadd_rn(xx, yy);
    float r  = __fsqrt_rn(r2);
    float d  = __fsqrt_rn(__fadd_rn(r2, zz));

    float wgt    = expf(-2.0f * d);       // value-level only; argmin-independent
    float depth1 = __fmul_rn(d, 80.0f);
    if (!(depth1 > 1.45f && depth1 < 80.0f)) wgt = 0.0f;

    // glibc msun f32 atan2 (host libm called by XLA's scalar atan2 lowering).
    float au = fd_atan2f(z, r);
    float av = fd_atan2f(y, x);

    // Robust window centering (staircase argmin is within +-1 of this center).
    int bh = 0; float bhd = 3.4e38f;
    for (int h = 0; h < Hd; ++h) {
        float dh = au - s_eu[h];
        float dd = dh * dh;
        if (dd < bhd) { bhd = dd; bh = h; }
    }
    int bw = 0; float bwd = 3.4e38f;
    for (int w = 0; w < Wd; ++w) {
        float dw = av - s_ev[w];
        float dd = dw * dw;
        if (dd < bwd) { bwd = dd; bw = w; }
    }

    int besti = argmin9(au, av, bh, bw, s_eu, s_eu2, s_ev, s_ev2);

    atomicAdd(&num[besti], __fmul_rn(wgt, depth1));
    atomicAdd(&den[besti], wgt);
}

__global__ __launch_bounds__(256) void finalize(
        const float* __restrict__ num,
        const float* __restrict__ den,
        float* __restrict__ out) {
    int i = blockIdx.x * blockDim.x + threadIdx.x;
    if (i >= HWd) return;
    float d2d = __fdiv_rn(num[i], __fadd_rn(den[i], 1e-8f));
    bool valid = (d2d != 0.0f);
    float nrm = __fdiv_rn(__fsub_rn(d2d, 1.45f), 78.55f);
    out[i]       = valid ? nrm : 1.0f;
    out[HWd + i] = valid ? 1.0f : 0.0f;
}

extern "C" void kernel_launch(void* const* d_in, const int* in_sizes, int n_in,
                              void* d_out, int out_size, void* d_ws, size_t ws_size,
                              hipStream_t stream) {
    const float* xyz   = (const float*)d_in[0];   // (1, 16384, 3)
    const float* angle = (const float*)d_in[1];   // (1, 2, 64, 256)
    float* out = (float*)d_out;                   // 32768 floats
    float* num = (float*)d_ws;
    float* den = num + HWd;

    hipMemsetAsync(d_ws, 0, 2 * HWd * sizeof(float), stream);
    proj_scatter<<<NPTS / 256, 256, 0, stream>>>(xyz, angle, num, den);
    finalize<<<HWd / 256, 256, 0, stream>>>(num, den, out);
}

// Round 8
// 73.196 us; speedup vs baseline: 1.0677x; 1.0677x over previous
//
#include <hip/hip_runtime.h>

#define Hd 64
#define Wd 256
#define HWd 16384
#define NPTS 16384

#define F(x) __int_as_float(x)

// ---- Device port of glibc/msun flt-32 atanf (5-coefficient version) ----
__device__ __forceinline__ float fd_atanf(float x) {
    int hx = __float_as_int(x);
    int ix = hx & 0x7fffffff;
    if (ix >= 0x4c800000) {                    // |x| >= 2^26
        if (ix > 0x7f800000) return x;         // NaN
        float r = __fadd_rn(F(0x3FC90FDA), F(0x33A22168));
        return (hx > 0) ? r : -r;
    }
    int id;
    if (ix < 0x3ee00000) {                     // |x| < 0.4375
        if (ix < 0x39800000) return x;         // |x| < 2^-12
        id = -1;
    } else {
        x = F(ix);                             // fabsf
        if (ix < 0x3f980000) {                 // |x| < 1.1875
            if (ix < 0x3f300000) {             // 7/16 <= |x| < 11/16
                id = 0;
                x = __fdiv_rn(__fsub_rn(__fadd_rn(x, x), 1.0f), __fadd_rn(2.0f, x));
            } else {                           // 11/16 <= |x| < 19/16
                id = 1;
                x = __fdiv_rn(__fsub_rn(x, 1.0f), __fadd_rn(x, 1.0f));
            }
        } else {
            if (ix < 0x401c0000) {             // |x| < 2.4375
                id = 2;
                x = __fdiv_rn(__fsub_rn(x, 1.5f), __fadd_rn(1.0f, __fmul_rn(1.5f, x)));
            } else {                           // 2.4375 <= |x| < 2^26
                id = 3;
                x = __fdiv_rn(-1.0f, x);
            }
        }
    }
    // msun 5-coefficient split polynomial
    float z = __fmul_rn(x, x);
    float w = __fmul_rn(z, z);
    float s1 = __fmul_rn(z, __fadd_rn(F(0x3EAAAAA3),
                    __fmul_rn(w, __fadd_rn(F(0x3E11F50D),
                    __fmul_rn(w, F(0x3D7CAC25))))));
    float s2 = __fmul_rn(w, __fadd_rn(F(0xBE4CCA17),
                    __fmul_rn(w, F(0xBDDA1247))));
    float ss = __fadd_rn(s1, s2);
    if (id < 0) return __fsub_rn(x, __fmul_rn(x, ss));
    const float athi[4] = {F(0x3EED6338), F(0x3F490FDA), F(0x3F7B985E), F(0x3FC90FDA)};
    const float atlo[4] = {F(0x31AC3769), F(0x33222168), F(0x33140FB4), F(0x33A22168)};
    float zr = __fsub_rn(athi[id], __fsub_rn(__fsub_rn(__fmul_rn(x, ss), atlo[id]), x));
    return (hx < 0) ? -zr : zr;
}

// ---- Device port of glibc/msun flt-32 atan2f wrapper ----
__device__ __forceinline__ float fd_atan2f(float y, float x) {
    const float pi     = F(0x40490FDB);
    const float pi_lo  = F(0xB3BBBD2E);
    const float pi_o_2 = F(0x3FC90FDB);
    int hx = __float_as_int(x), ix = hx & 0x7fffffff;
    int hy = __float_as_int(y), iy = hy & 0x7fffffff;
    if (ix > 0x7f800000 || iy > 0x7f800000) return x + y;  // NaN
    if (hx == 0x3f800000) return fd_atanf(y);              // x == 1.0
    int m = ((hy >> 31) & 1) | ((hx >> 30) & 2);
    if (iy == 0) {
        switch (m) { case 0: case 1: return y; case 2: return pi; default: return -pi; }
    }
    if (ix == 0) return (hy < 0) ? -pi_o_2 : pi_o_2;
    if (ix == 0x7f800000) {
        if (iy == 0x7f800000) {
            switch (m) {
                case 0: return F(0x3F490FDB);
                case 1: return -F(0x3F490FDB);
                case 2: return __fmul_rn(3.0f, F(0x3F490FDB));
                default: return -__fmul_rn(3.0f, F(0x3F490FDB));
            }
        } else {
            switch (m) { case 0: return 0.0f; case 1: return -0.0f; case 2: return pi; default: return -pi; }
        }
    }
    if (iy == 0x7f800000) return (hy < 0) ? -pi_o_2 : pi_o_2;
    int k = (iy - ix) >> 23;      // approx exponent difference
    float z;
    if (k > 26) { z = __fadd_rn(pi_o_2, __fmul_rn(0.5f, pi_lo)); m &= 1; }
    else if (hx < 0 && k < -26) z = 0.0f;
    else z = fd_atanf(__fdiv_rn(F(iy), F(ix)));  // atanf(fabsf(y/x))
    switch (m) {
        case 0: return z;
        case 1: return -z;
        case 2: return __fsub_rn(pi, __fsub_rn(z, pi_lo));
        default: return __fsub_rn(__fsub_rn(z, pi_lo), pi);
    }
}

__global__ __launch_bounds__(256) void proj_scatter(
        const float* __restrict__ xyz,
        const float* __restrict__ angle,
        float* __restrict__ num,
        float* __restrict__ den) {
    __shared__ float s_eu[Hd], s_eu2[Hd];
    __shared__ float s_ev[Wd], s_ev2[Wd];

    int t = threadIdx.x;
    if (t < Hd) {
        float e = angle[t * Wd];          // channel 0 (elev), row t, col 0
        s_eu[t]  = e;
        s_eu2[t] = __fmul_rn(e, e);
    }
    {
        float a = angle[HWd + t];         // channel 1 (azim), row 0, col t
        s_ev[t]  = a;
        s_ev2[t] = __fmul_rn(a, a);
    }
    __syncthreads();

    int n = blockIdx.x * blockDim.x + t;
    if (n >= NPTS) return;

    float x = xyz[3 * n + 0];
    float y = xyz[3 * n + 1];
    float z = xyz[3 * n + 2];

    // Replicate f32 norm rounding order: ((x^2+y^2)+z^2)
    float xx = __fmul_rn(x, x);
    float yy = __fmul_rn(y, y);
    float zz = __fmul_rn(z, z);
    float r2 = __fadd_rn(xx, yy);
    float r  = __fsqrt_rn(r2);
    float d  = __fsqrt_rn(__fadd_rn(r2, zz));

    float wgt    = expf(-2.0f * d);       // value-level only; argmin-independent
    float depth1 = __fmul_rn(d, 80.0f);
    if (!(depth1 > 1.45f && depth1 < 80.0f)) wgt = 0.0f;

    // Frozen R7 semantics: glibc msun f32 atan2 (bit-matches host libm).
    float au = fd_atan2f(z, r);
    float av = fd_atan2f(y, x);

    // Analytic separable-nearest center (replaces the 64+256 serial scans).
    // Grid is affine linspace: center = round((a - g0)/step), steps in f64
    // from the loaded f32 endpoints (linspace deviates from affine by ~1 ulp
    // << half-cell). The exact-replica argmin below uses a +-2 window, which
    // provably contains the ref's global staircase argmin (noise 2e-6 <<
    // two-cell gap 1.2e-4), absorbing any center rounding ambiguity.
    double su = ((double)s_eu[Hd - 1] - (double)s_eu[0]) / (double)(Hd - 1);
    double sv = ((double)s_ev[Wd - 1] - (double)s_ev[0]) / (double)(Wd - 1);
    int bh = __double2int_rn(((double)au - (double)s_eu[0]) / su);
    int bw = __double2int_rn(((double)av - (double)s_ev[0]) / sv);
    bh = bh < 0 ? 0 : (bh > Hd - 1 ? Hd - 1 : bh);
    bw = bw < 0 ? 0 : (bw > Wd - 1 ? Wd - 1 : bw);

    // Exact f32 replica of ref's expansion-formula d2 argmin, 5x5 window,
    // FMA-accumulated dot (Eigen GEMM), first-smallest-index tie-break.
    float asq = __fadd_rn(__fmul_rn(au, au), __fmul_rn(av, av));
    float bestd = 3.4e38f; int besti = 0x7fffffff;
    #pragma unroll
    for (int dh = -2; dh <= 2; ++dh) {
        int hh = bh + dh; hh = hh < 0 ? 0 : (hh > Hd - 1 ? Hd - 1 : hh);
        #pragma unroll
        for (int dw = -2; dw <= 2; ++dw) {
            int ww = bw + dw; ww = ww < 0 ? 0 : (ww > Wd - 1 ? Wd - 1 : ww);
            float gsq = __fadd_rn(s_eu2[hh], s_ev2[ww]);
            float dot = __builtin_fmaf(av, s_ev[ww], __fmul_rn(au, s_eu[hh]));
            float d2  = __fsub_rn(__fadd_rn(asq, gsq), __fmul_rn(2.0f, dot));
            int idx = hh * Wd + ww;
            if (d2 < bestd || (d2 == bestd && idx < besti)) { bestd = d2; besti = idx; }
        }
    }

    atomicAdd(&num[besti], __fmul_rn(wgt, depth1));
    atomicAdd(&den[besti], wgt);
}

__global__ __launch_bounds__(256) void finalize(
        const float* __restrict__ num,
        const float* __restrict__ den,
        float* __restrict__ out) {
    int i = blockIdx.x * blockDim.x + threadIdx.x;
    if (i >= HWd) return;
    float d2d = __fdiv_rn(num[i], __fadd_rn(den[i], 1e-8f));
    bool valid = (d2d != 0.0f);
    float nrm = __fdiv_rn(__fsub_rn(d2d, 1.45f), 78.55f);
    out[i]       = valid ? nrm : 1.0f;
    out[HWd + i] = valid ? 1.0f : 0.0f;
}

extern "C" void kernel_launch(void* const* d_in, const int* in_sizes, int n_in,
                              void* d_out, int out_size, void* d_ws, size_t ws_size,
                              hipStream_t stream) {
    const float* xyz   = (const float*)d_in[0];   // (1, 16384, 3)
    const float* angle = (const float*)d_in[1];   // (1, 2, 64, 256)
    float* out = (float*)d_out;                   // 32768 floats
    float* num = (float*)d_ws;
    float* den = num + HWd;

    hipMemsetAsync(d_ws, 0, 2 * HWd * sizeof(float), stream);
    proj_scatter<<<NPTS / 256, 256, 0, stream>>>(xyz, angle, num, den);
    finalize<<<HWd / 256, 256, 0, stream>>>(num, den, out);
}